// Round 3
// baseline (323.270 us; speedup 1.0000x reference)
//
#include <hip/hip_runtime.h>
#include <math.h>

#define HD    128
#define NQH   32
#define NKVH  8
#define GQA   4
#define PBLK  16      // paged cache block size
#define MAXNB 512     // max block-table entries cached in LDS

typedef float f4 __attribute__((ext_vector_type(4)));
typedef float f2 __attribute__((ext_vector_type(2)));

// token base pointer (K or V) for token t; t == T means "current" k/v
__device__ __forceinline__ const float* tok_base(
    const float* __restrict__ cache, const float* __restrict__ cur,
    const int* __restrict__ btrow, int t, int T, int b, int h)
{
    if (t == T) return cur + ((size_t)b * NKVH + h) * HD;
    int blk = btrow[t >> 4];
    return cache + (((size_t)blk * PBLK + (t & (PBLK - 1))) * NKVH + h) * HD;
}

// interleaved rope table: tab[t*128 + 2*f] = cos(t*invf[f]), [2*f+1] = sin
__global__ void rope_table_kernel(float* __restrict__ tab, int T) {
    int idx = blockIdx.x * blockDim.x + threadIdx.x;
    int total = (T + 1) * 64;
    if (idx >= total) return;
    int t = idx >> 6;
    int f = idx & 63;
    double ang = (double)t * pow(10000.0, -(double)f / 64.0);
    tab[(size_t)t * 128 + 2 * f]     = (float)cos(ang);
    tab[(size_t)t * 128 + 2 * f + 1] = (float)sin(ang);
}

// grid: (b*NKVH + h)*S + s ; 1024 threads; each half-wave strides tokens by 32
__global__ __launch_bounds__(1024, 8) void paged_attn_kernel(
    const float* __restrict__ q,
    const float* __restrict__ kcur,
    const float* __restrict__ vcur,
    const float* __restrict__ kc,
    const float* __restrict__ vc,
    const int* __restrict__ bt,
    const float* __restrict__ tab,
    float* __restrict__ out,       // used when S == 1
    float* __restrict__ pm,        // [nblk][4]
    float* __restrict__ pl,        // [nblk][4]
    float* __restrict__ po,        // [nblk][4][HD]
    int T, int nb, int S, int useTable)
{
    const int bh = blockIdx.x / S;
    const int s  = blockIdx.x - bh * S;
    const int b  = bh >> 3;
    const int h  = bh & 7;
    const int tid = threadIdx.x;
    const int hw  = tid >> 5;        // half-wave id 0..31
    const int il  = tid & 31;        // lane within half-wave
    const int d0v = il << 2;         // V/output dims [d0v, d0v+4)
    const int dk  = il << 1;         // K dims: {dk,dk+1} and {64+dk, 64+dk+1}

    const int total = T + 1;
    const int chunk = (total + S - 1) / S;
    const int lo    = s * chunk;
    const int hi    = min(lo + chunk, total);

    // cache block table row in LDS
    __shared__ int sbt[MAXNB];
    const int* btrow = bt + (size_t)b * nb;
    if (nb <= MAXNB) {
        for (int i = tid; i < nb; i += 1024) sbt[i] = btrow[i];
        __syncthreads();
        btrow = sbt;
    }

    float invf0 = 0.f, invf1 = 0.f;
    if (!useTable) {
        invf0 = exp2f(-(float)(dk)     * (13.287712379549449f / 64.0f));
        invf1 = exp2f(-(float)(dk + 1) * (13.287712379549449f / 64.0f));
    }

    // --- rope current q (4 GQA heads) at position T, in-lane rotate-half ---
    f4 qr[4];
    {
        f4 cs;
        if (useTable) {
            cs = *(const f4*)(tab + (size_t)T * 128 + 4 * il);
        } else {
            float ss, cc;
            sincosf((float)T * invf0, &ss, &cc); cs.x = cc; cs.y = ss;
            sincosf((float)T * invf1, &ss, &cc); cs.z = cc; cs.w = ss;
        }
        const float* qb = q + ((size_t)b * NQH + h * GQA) * HD;
#pragma unroll
        for (int g = 0; g < 4; ++g) {
            f2 xlo = *(const f2*)(qb + (size_t)g * HD + dk);
            f2 xhi = *(const f2*)(qb + (size_t)g * HD + 64 + dk);
            qr[g].x = xlo.x * cs.x - xhi.x * cs.y;
            qr[g].y = xlo.y * cs.z - xhi.y * cs.w;
            qr[g].z = xhi.x * cs.x + xlo.x * cs.y;
            qr[g].w = xhi.y * cs.z + xlo.y * cs.w;
        }
    }

    const float scale = 0.08838834764831845f;  // 128^-0.5
    float m[4] = {-INFINITY, -INFINITY, -INFINITY, -INFINITY};
    float l[4] = {0.f, 0.f, 0.f, 0.f};
    f4 o[4] = {};

    // --- main loop over this split's tokens ---
    int t = lo + hw;
    f2 klo = {}, khi = {};
    f4 vv = {};
    if (t < hi) {
        const float* kb = tok_base(kc, kcur, btrow, t, T, b, h);
        const float* vb = tok_base(vc, vcur, btrow, t, T, b, h);
        klo = *(const f2*)(kb + dk);
        khi = *(const f2*)(kb + 64 + dk);
        vv  = *(const f4*)(vb + d0v);
    }
    for (; t < hi; t += 32) {
        // prefetch next token
        const int tn = t + 32;
        f2 klon = {}, khin = {};
        f4 vn = {};
        if (tn < hi) {
            const float* kb = tok_base(kc, kcur, btrow, tn, T, b, h);
            const float* vb = tok_base(vc, vcur, btrow, tn, T, b, h);
            klon = *(const f2*)(kb + dk);
            khin = *(const f2*)(kb + 64 + dk);
            vn   = *(const f4*)(vb + d0v);
        }

        f4 cs;
        if (useTable) {
            cs = *(const f4*)(tab + (size_t)t * 128 + 4 * il);
        } else {
            float ss, cc;
            sincosf((float)t * invf0, &ss, &cc); cs.x = cc; cs.y = ss;
            sincosf((float)t * invf1, &ss, &cc); cs.z = cc; cs.w = ss;
        }
        f4 kr;
        kr.x = klo.x * cs.x - khi.x * cs.y;
        kr.y = klo.y * cs.z - khi.y * cs.w;
        kr.z = khi.x * cs.x + klo.x * cs.y;
        kr.w = khi.y * cs.z + klo.y * cs.w;

        float s0 = qr[0].x * kr.x + qr[0].y * kr.y + qr[0].z * kr.z + qr[0].w * kr.w;
        float s1 = qr[1].x * kr.x + qr[1].y * kr.y + qr[1].z * kr.z + qr[1].w * kr.w;
        float s2 = qr[2].x * kr.x + qr[2].y * kr.y + qr[2].z * kr.z + qr[2].w * kr.w;
        float s3 = qr[3].x * kr.x + qr[3].y * kr.y + qr[3].z * kr.z + qr[3].w * kr.w;
#pragma unroll
        for (int msk = 16; msk >= 1; msk >>= 1) {
            s0 += __shfl_xor(s0, msk);
            s1 += __shfl_xor(s1, msk);
            s2 += __shfl_xor(s2, msk);
            s3 += __shfl_xor(s3, msk);
        }
        float sarr[4] = {s0, s1, s2, s3};
#pragma unroll
        for (int g = 0; g < 4; ++g) {
            float sc = sarr[g] * scale;
            if (sc > m[g]) {                     // lazy rescale: rare (~log T times)
                float corr = __expf(m[g] - sc);
                l[g] *= corr;
                o[g] *= corr;
                m[g] = sc;
            }
            float p = __expf(sc - m[g]);
            l[g] += p;
            o[g] += p * vv;
        }
        klo = klon; khi = khin; vv = vn;
    }

    // --- combine the two half-waves of each wave ---
#pragma unroll
    for (int g = 0; g < 4; ++g) {
        float mo = __shfl_xor(m[g], 32);
        float M  = fmaxf(m[g], mo);
        float w  = (m[g] > -INFINITY) ? __expf(m[g] - M) : 0.f;
        float lw = l[g] * w;
        float Lc = lw + __shfl_xor(lw, 32);
        f4 ow = o[g] * w;
        f4 Oc;
        Oc.x = ow.x + __shfl_xor(ow.x, 32);
        Oc.y = ow.y + __shfl_xor(ow.y, 32);
        Oc.z = ow.z + __shfl_xor(ow.z, 32);
        Oc.w = ow.w + __shfl_xor(ow.w, 32);
        m[g] = M; l[g] = Lc; o[g] = Oc;
    }

    // --- cross-wave flash combine via LDS ---
    __shared__ float lm[16][4];
    __shared__ float ll[16][4];
    __shared__ float lodata[16][4][HD];
    const int w = tid >> 6;
    if ((tid & 32) == 0) {
        if (il == 0) {
#pragma unroll
            for (int g = 0; g < 4; ++g) { lm[w][g] = m[g]; ll[w][g] = l[g]; }
        }
#pragma unroll
        for (int g = 0; g < 4; ++g)
            *(f4*)(&lodata[w][g][d0v]) = o[g];
    }
    __syncthreads();

    if (tid < 512) {
        int g = tid >> 7;
        int d = tid & 127;
        float M = -INFINITY;
#pragma unroll
        for (int i = 0; i < 16; ++i) M = fmaxf(M, lm[i][g]);
        float L = 0.f, O = 0.f;
#pragma unroll
        for (int i = 0; i < 16; ++i) {
            float wgt = __expf(lm[i][g] - M);
            L += wgt * ll[i][g];
            O += wgt * lodata[i][g][d];
        }
        if (S == 1) {
            out[(size_t)b * (NQH * HD) + (size_t)(h * GQA + g) * HD + d] = O / L;
        } else {
            int pidx = blockIdx.x * 4 + g;
            po[(size_t)pidx * HD + d] = O;
            if (d == 0) { pm[pidx] = M; pl[pidx] = L; }
        }
    }
}

__global__ void combine_kernel(
    const float* __restrict__ pm,
    const float* __restrict__ pl,
    const float* __restrict__ po,
    float* __restrict__ out, int S)
{
    int i = blockIdx.x * blockDim.x + threadIdx.x;   // over B*NQH*HD
    int d  = i & 127;
    int qh = (i >> 7) & 31;
    int b  = i >> 12;
    int h  = qh >> 2;
    int g  = qh & 3;
    int base = ((b * NKVH + h) * S) * 4 + g;
    float M = -INFINITY;
    for (int s = 0; s < S; ++s) M = fmaxf(M, pm[base + s * 4]);
    float L = 0.f, O = 0.f;
    for (int s = 0; s < S; ++s) {
        float wgt = __expf(pm[base + s * 4] - M);
        L += wgt * pl[base + s * 4];
        O += wgt * po[(size_t)(base + s * 4) * HD + d];
    }
    out[i] = O / L;
}

extern "C" void kernel_launch(void* const* d_in, const int* in_sizes, int n_in,
                              void* d_out, int out_size, void* d_ws, size_t ws_size,
                              hipStream_t stream) {
    const float* q  = (const float*)d_in[0];
    const float* k  = (const float*)d_in[1];
    const float* v  = (const float*)d_in[2];
    const float* kc = (const float*)d_in[3];
    const float* vc = (const float*)d_in[4];
    const int*   bt = (const int*)d_in[5];
    int B  = in_sizes[0] / (NQH * HD);
    int nb = in_sizes[5] / B;
    int T  = nb * PBLK;

    float* out = (float*)d_out;
    char*  ws  = (char*)d_ws;

    size_t tabBytes = (size_t)(T + 1) * 128 * sizeof(float);
    size_t off = (tabBytes + 255) & ~(size_t)255;

    int S = 4;
    int nblk = B * NKVH * S;
    size_t pmB = (size_t)nblk * 4 * sizeof(float);
    size_t poB = (size_t)nblk * 4 * HD * sizeof(float);
    size_t need = off + 2 * pmB + poB;

    int useTable = (ws_size >= tabBytes) ? 1 : 0;
    if (ws_size < need) S = 1;   // fallback: single-pass direct write

    float* tab = (float*)ws;
    float* pm  = (float*)(ws + off);
    float* pl  = (float*)(ws + off + pmB);
    float* po  = (float*)(ws + off + 2 * pmB);

    if (useTable) {
        int total = (T + 1) * 64;
        rope_table_kernel<<<(total + 255) / 256, 256, 0, stream>>>(tab, T);
    }
    paged_attn_kernel<<<B * NKVH * S, 1024, 0, stream>>>(
        q, k, v, kc, vc, bt, tab, out, pm, pl, po, T, nb, S, useTable);
    if (S > 1) {
        int totalOut = B * NQH * HD;
        combine_kernel<<<(totalOut + 255) / 256, 256, 0, stream>>>(pm, pl, po, out, S);
    }
}

// Round 4
// 132.728 us; speedup vs baseline: 2.4356x; 2.4356x over previous
//
#include <hip/hip_runtime.h>
#include <math.h>

#define HD    128
#define NQH   32
#define NKVH  8
#define GQA   4
#define PBLK  16      // paged cache block size
#define MAXNB 512     // max block-table entries cached in LDS

typedef float f4 __attribute__((ext_vector_type(4)));
typedef float f2 __attribute__((ext_vector_type(2)));

// token base pointer (K or V) for token t; t == T means "current" k/v
__device__ __forceinline__ const float* tok_base(
    const float* __restrict__ cache, const float* __restrict__ cur,
    const int* __restrict__ btrow, int t, int T, int b, int h)
{
    if (t == T) return cur + ((size_t)b * NKVH + h) * HD;
    int blk = btrow[t >> 4];
    return cache + (((size_t)blk * PBLK + (t & (PBLK - 1))) * NKVH + h) * HD;
}

// interleaved rope table: tab[t*128 + 2*f] = cos(t*invf[f]), [2*f+1] = sin
__global__ void rope_table_kernel(float* __restrict__ tab, int T) {
    int idx = blockIdx.x * blockDim.x + threadIdx.x;
    int total = (T + 1) * 64;
    if (idx >= total) return;
    int t = idx >> 6;
    int f = idx & 63;
    double ang = (double)t * pow(10000.0, -(double)f / 64.0);
    tab[(size_t)t * 128 + 2 * f]     = (float)cos(ang);
    tab[(size_t)t * 128 + 2 * f + 1] = (float)sin(ang);
}

// grid: (b*NKVH + h)*S + s ; 1024 threads; each half-wave strides tokens by 32
// NOTE: no min-waves in launch_bounds — forcing 8 waves/EU capped VGPR at 32
// and caused 250 MB of scratch-spill writes (round-3 regression). At natural
// ~60 VGPR the HW already fits 2 blocks/CU (8 waves/SIMD, 71 KB LDS).
__global__ __launch_bounds__(1024) void paged_attn_kernel(
    const float* __restrict__ q,
    const float* __restrict__ kcur,
    const float* __restrict__ vcur,
    const float* __restrict__ kc,
    const float* __restrict__ vc,
    const int* __restrict__ bt,
    const float* __restrict__ tab,
    float* __restrict__ out,       // used when S == 1
    float* __restrict__ pm,        // [nblk][4]
    float* __restrict__ pl,        // [nblk][4]
    float* __restrict__ po,        // [nblk][4][HD]
    int T, int nb, int S, int useTable)
{
    const int bh = blockIdx.x / S;
    const int s  = blockIdx.x - bh * S;
    const int b  = bh >> 3;
    const int h  = bh & 7;
    const int tid = threadIdx.x;
    const int hw  = tid >> 5;        // half-wave id 0..31
    const int il  = tid & 31;        // lane within half-wave
    const int d0v = il << 2;         // V/output dims [d0v, d0v+4)
    const int dk  = il << 1;         // K dims: {dk,dk+1} and {64+dk, 64+dk+1}

    const int total = T + 1;
    const int chunk = (total + S - 1) / S;
    const int lo    = s * chunk;
    const int hi    = min(lo + chunk, total);

    // cache block table row in LDS
    __shared__ int sbt[MAXNB];
    const int* btrow = bt + (size_t)b * nb;
    if (nb <= MAXNB) {
        for (int i = tid; i < nb; i += 1024) sbt[i] = btrow[i];
        __syncthreads();
        btrow = sbt;
    }

    float invf0 = 0.f, invf1 = 0.f;
    if (!useTable) {
        invf0 = exp2f(-(float)(dk)     * (13.287712379549449f / 64.0f));
        invf1 = exp2f(-(float)(dk + 1) * (13.287712379549449f / 64.0f));
    }

    // --- rope current q (4 GQA heads) at position T, in-lane rotate-half ---
    f4 qr[4];
    {
        f4 cs;
        if (useTable) {
            cs = *(const f4*)(tab + (size_t)T * 128 + 4 * il);
        } else {
            float ss, cc;
            sincosf((float)T * invf0, &ss, &cc); cs.x = cc; cs.y = ss;
            sincosf((float)T * invf1, &ss, &cc); cs.z = cc; cs.w = ss;
        }
        const float* qb = q + ((size_t)b * NQH + h * GQA) * HD;
#pragma unroll
        for (int g = 0; g < 4; ++g) {
            f2 xlo = *(const f2*)(qb + (size_t)g * HD + dk);
            f2 xhi = *(const f2*)(qb + (size_t)g * HD + 64 + dk);
            qr[g].x = xlo.x * cs.x - xhi.x * cs.y;
            qr[g].y = xlo.y * cs.z - xhi.y * cs.w;
            qr[g].z = xhi.x * cs.x + xlo.x * cs.y;
            qr[g].w = xhi.y * cs.z + xlo.y * cs.w;
        }
    }

    const float scale = 0.08838834764831845f;  // 128^-0.5
    float m[4] = {-INFINITY, -INFINITY, -INFINITY, -INFINITY};
    float l[4] = {0.f, 0.f, 0.f, 0.f};
    f4 o[4] = {};

    // --- main loop over this split's tokens ---
    int t = lo + hw;
    f2 klo = {}, khi = {};
    f4 vv = {};
    if (t < hi) {
        const float* kb = tok_base(kc, kcur, btrow, t, T, b, h);
        const float* vb = tok_base(vc, vcur, btrow, t, T, b, h);
        klo = *(const f2*)(kb + dk);
        khi = *(const f2*)(kb + 64 + dk);
        vv  = *(const f4*)(vb + d0v);
    }
    for (; t < hi; t += 32) {
        // prefetch next token
        const int tn = t + 32;
        f2 klon = {}, khin = {};
        f4 vn = {};
        if (tn < hi) {
            const float* kb = tok_base(kc, kcur, btrow, tn, T, b, h);
            const float* vb = tok_base(vc, vcur, btrow, tn, T, b, h);
            klon = *(const f2*)(kb + dk);
            khin = *(const f2*)(kb + 64 + dk);
            vn   = *(const f4*)(vb + d0v);
        }

        f4 cs;
        if (useTable) {
            cs = *(const f4*)(tab + (size_t)t * 128 + 4 * il);
        } else {
            float ss, cc;
            sincosf((float)t * invf0, &ss, &cc); cs.x = cc; cs.y = ss;
            sincosf((float)t * invf1, &ss, &cc); cs.z = cc; cs.w = ss;
        }
        f4 kr;
        kr.x = klo.x * cs.x - khi.x * cs.y;
        kr.y = klo.y * cs.z - khi.y * cs.w;
        kr.z = khi.x * cs.x + klo.x * cs.y;
        kr.w = khi.y * cs.z + klo.y * cs.w;

        float s0 = qr[0].x * kr.x + qr[0].y * kr.y + qr[0].z * kr.z + qr[0].w * kr.w;
        float s1 = qr[1].x * kr.x + qr[1].y * kr.y + qr[1].z * kr.z + qr[1].w * kr.w;
        float s2 = qr[2].x * kr.x + qr[2].y * kr.y + qr[2].z * kr.z + qr[2].w * kr.w;
        float s3 = qr[3].x * kr.x + qr[3].y * kr.y + qr[3].z * kr.z + qr[3].w * kr.w;
#pragma unroll
        for (int msk = 16; msk >= 1; msk >>= 1) {
            s0 += __shfl_xor(s0, msk);
            s1 += __shfl_xor(s1, msk);
            s2 += __shfl_xor(s2, msk);
            s3 += __shfl_xor(s3, msk);
        }
        float sarr[4] = {s0, s1, s2, s3};
#pragma unroll
        for (int g = 0; g < 4; ++g) {
            float sc = sarr[g] * scale;
            if (sc > m[g]) {                     // lazy rescale: rare (~log T times)
                float corr = __expf(m[g] - sc);
                l[g] *= corr;
                o[g] *= corr;
                m[g] = sc;
            }
            float p = __expf(sc - m[g]);
            l[g] += p;
            o[g] += p * vv;
        }
        klo = klon; khi = khin; vv = vn;
    }

    // --- combine the two half-waves of each wave ---
#pragma unroll
    for (int g = 0; g < 4; ++g) {
        float mo = __shfl_xor(m[g], 32);
        float M  = fmaxf(m[g], mo);
        float w  = (m[g] > -INFINITY) ? __expf(m[g] - M) : 0.f;
        float lw = l[g] * w;
        float Lc = lw + __shfl_xor(lw, 32);
        f4 ow = o[g] * w;
        f4 Oc;
        Oc.x = ow.x + __shfl_xor(ow.x, 32);
        Oc.y = ow.y + __shfl_xor(ow.y, 32);
        Oc.z = ow.z + __shfl_xor(ow.z, 32);
        Oc.w = ow.w + __shfl_xor(ow.w, 32);
        m[g] = M; l[g] = Lc; o[g] = Oc;
    }

    // --- cross-wave flash combine via LDS ---
    __shared__ float lm[16][4];
    __shared__ float ll[16][4];
    __shared__ float lodata[16][4][HD];
    const int w = tid >> 6;
    if ((tid & 32) == 0) {
        if (il == 0) {
#pragma unroll
            for (int g = 0; g < 4; ++g) { lm[w][g] = m[g]; ll[w][g] = l[g]; }
        }
#pragma unroll
        for (int g = 0; g < 4; ++g)
            *(f4*)(&lodata[w][g][d0v]) = o[g];
    }
    __syncthreads();

    if (tid < 512) {
        int g = tid >> 7;
        int d = tid & 127;
        float M = -INFINITY;
#pragma unroll
        for (int i = 0; i < 16; ++i) M = fmaxf(M, lm[i][g]);
        float L = 0.f, O = 0.f;
#pragma unroll
        for (int i = 0; i < 16; ++i) {
            float wgt = __expf(lm[i][g] - M);
            L += wgt * ll[i][g];
            O += wgt * lodata[i][g][d];
        }
        if (S == 1) {
            out[(size_t)b * (NQH * HD) + (size_t)(h * GQA + g) * HD + d] = O / L;
        } else {
            int pidx = blockIdx.x * 4 + g;
            po[(size_t)pidx * HD + d] = O;
            if (d == 0) { pm[pidx] = M; pl[pidx] = L; }
        }
    }
}

__global__ void combine_kernel(
    const float* __restrict__ pm,
    const float* __restrict__ pl,
    const float* __restrict__ po,
    float* __restrict__ out, int S)
{
    int i = blockIdx.x * blockDim.x + threadIdx.x;   // over B*NQH*HD
    int d  = i & 127;
    int qh = (i >> 7) & 31;
    int b  = i >> 12;
    int h  = qh >> 2;
    int g  = qh & 3;
    int base = ((b * NKVH + h) * S) * 4 + g;
    float M = -INFINITY;
    for (int s = 0; s < S; ++s) M = fmaxf(M, pm[base + s * 4]);
    float L = 0.f, O = 0.f;
    for (int s = 0; s < S; ++s) {
        float wgt = __expf(pm[base + s * 4] - M);
        L += wgt * pl[base + s * 4];
        O += wgt * po[(size_t)(base + s * 4) * HD + d];
    }
    out[i] = O / L;
}

extern "C" void kernel_launch(void* const* d_in, const int* in_sizes, int n_in,
                              void* d_out, int out_size, void* d_ws, size_t ws_size,
                              hipStream_t stream) {
    const float* q  = (const float*)d_in[0];
    const float* k  = (const float*)d_in[1];
    const float* v  = (const float*)d_in[2];
    const float* kc = (const float*)d_in[3];
    const float* vc = (const float*)d_in[4];
    const int*   bt = (const int*)d_in[5];
    int B  = in_sizes[0] / (NQH * HD);
    int nb = in_sizes[5] / B;
    int T  = nb * PBLK;

    float* out = (float*)d_out;
    char*  ws  = (char*)d_ws;

    size_t tabBytes = (size_t)(T + 1) * 128 * sizeof(float);
    size_t off = (tabBytes + 255) & ~(size_t)255;

    int S = 4;
    int nblk = B * NKVH * S;
    size_t pmB = (size_t)nblk * 4 * sizeof(float);
    size_t poB = (size_t)nblk * 4 * HD * sizeof(float);
    size_t need = off + 2 * pmB + poB;

    int useTable = (ws_size >= tabBytes) ? 1 : 0;
    if (ws_size < need) S = 1;   // fallback: single-pass direct write

    float* tab = (float*)ws;
    float* pm  = (float*)(ws + off);
    float* pl  = (float*)(ws + off + pmB);
    float* po  = (float*)(ws + off + 2 * pmB);

    if (useTable) {
        int total = (T + 1) * 64;
        rope_table_kernel<<<(total + 255) / 256, 256, 0, stream>>>(tab, T);
    }
    paged_attn_kernel<<<B * NKVH * S, 1024, 0, stream>>>(
        q, k, v, kc, vc, bt, tab, out, pm, pl, po, T, nb, S, useTable);
    if (S > 1) {
        int totalOut = B * NQH * HD;
        combine_kernel<<<(totalOut + 255) / 256, 256, 0, stream>>>(pm, pl, po, out, S);
    }
}

// Round 5
// 129.176 us; speedup vs baseline: 2.5026x; 1.0275x over previous
//
#include <hip/hip_runtime.h>
#include <math.h>

#define HD    128
#define NQH   32
#define NKVH  8
#define GQA   4
#define PBLK  16      // paged cache block size
#define MAXNB 512     // max block-table entries cached in LDS

typedef float f4 __attribute__((ext_vector_type(4)));
typedef float f2 __attribute__((ext_vector_type(2)));

// token base pointer (K or V) for token t; t == T means "current" k/v
__device__ __forceinline__ const float* tok_base(
    const float* __restrict__ cache, const float* __restrict__ cur,
    const int* __restrict__ btrow, int t, int T, int b, int h)
{
    if (t == T) return cur + ((size_t)b * NKVH + h) * HD;
    int blk = btrow[t >> 4];
    return cache + (((size_t)blk * PBLK + (t & (PBLK - 1))) * NKVH + h) * HD;
}

// interleaved rope table: tab[t*128 + 2*f] = cos(t*invf[f]), [2*f+1] = sin
__global__ void rope_table_kernel(float* __restrict__ tab, int T) {
    int idx = blockIdx.x * blockDim.x + threadIdx.x;
    int total = (T + 1) * 64;
    if (idx >= total) return;
    int t = idx >> 6;
    int f = idx & 63;
    double ang = (double)t * pow(10000.0, -(double)f / 64.0);
    tab[(size_t)t * 128 + 2 * f]     = (float)cos(ang);
    tab[(size_t)t * 128 + 2 * f + 1] = (float)sin(ang);
}

// grid: (b*NKVH + h)*S + s ; 256 threads (4 waves) per block.
// 1024-thread/35KB blocks only got 1 slot/CU (44% occupancy, rounds 2-4);
// 256-thread/10KB blocks allow 8 workgroups = 32 waves/CU.
__global__ __launch_bounds__(256) void paged_attn_kernel(
    const float* __restrict__ q,
    const float* __restrict__ kcur,
    const float* __restrict__ vcur,
    const float* __restrict__ kc,
    const float* __restrict__ vc,
    const int* __restrict__ bt,
    const float* __restrict__ tab,
    float* __restrict__ out,       // used when S == 1
    float* __restrict__ pm,        // [nblk][4]
    float* __restrict__ pl,        // [nblk][4]
    float* __restrict__ po,        // [nblk][4][HD]
    int T, int nb, int S, int useTable)
{
    const int bh = blockIdx.x / S;
    const int s  = blockIdx.x - bh * S;
    const int b  = bh >> 3;
    const int h  = bh & 7;
    const int tid = threadIdx.x;
    const int hw  = tid >> 5;        // half-wave id 0..7
    const int il  = tid & 31;        // lane within half-wave
    const int d0v = il << 2;         // V/output dims [d0v, d0v+4)
    const int dk  = il << 1;         // K dims: {dk,dk+1} and {64+dk, 64+dk+1}

    const int total = T + 1;
    const int chunk = (total + S - 1) / S;
    const int lo    = s * chunk;
    const int hi    = min(lo + chunk, total);

    // cache block table row in LDS
    __shared__ int sbt[MAXNB];
    const int* btrow = bt + (size_t)b * nb;
    if (nb <= MAXNB) {
        for (int i = tid; i < nb; i += 256) sbt[i] = btrow[i];
        __syncthreads();
        btrow = sbt;
    }

    float invf0 = 0.f, invf1 = 0.f;
    if (!useTable) {
        invf0 = exp2f(-(float)(dk)     * (13.287712379549449f / 64.0f));
        invf1 = exp2f(-(float)(dk + 1) * (13.287712379549449f / 64.0f));
    }

    const float scale = 0.08838834764831845f;  // 128^-0.5

    // --- rope current q (4 GQA heads) at position T, in-lane rotate-half;
    //     fold the 1/sqrt(d) scale into q ---
    f4 qr[4];
    {
        f4 cs;
        if (useTable) {
            cs = *(const f4*)(tab + (size_t)T * 128 + 4 * il);
        } else {
            float ss, cc;
            sincosf((float)T * invf0, &ss, &cc); cs.x = cc; cs.y = ss;
            sincosf((float)T * invf1, &ss, &cc); cs.z = cc; cs.w = ss;
        }
        const float* qb = q + ((size_t)b * NQH + h * GQA) * HD;
#pragma unroll
        for (int g = 0; g < 4; ++g) {
            f2 xlo = *(const f2*)(qb + (size_t)g * HD + dk);
            f2 xhi = *(const f2*)(qb + (size_t)g * HD + 64 + dk);
            qr[g].x = (xlo.x * cs.x - xhi.x * cs.y) * scale;
            qr[g].y = (xlo.y * cs.z - xhi.y * cs.w) * scale;
            qr[g].z = (xhi.x * cs.x + xlo.x * cs.y) * scale;
            qr[g].w = (xhi.y * cs.z + xlo.y * cs.w) * scale;
        }
    }

    float m[4] = {-INFINITY, -INFINITY, -INFINITY, -INFINITY};
    float l[4] = {0.f, 0.f, 0.f, 0.f};
    f4 o[4] = {};

    // --- main loop over this split's tokens; half-waves stride by 8 ---
    int t = lo + hw;
    f2 klo = {}, khi = {};
    f4 vv = {};
    if (t < hi) {
        const float* kb = tok_base(kc, kcur, btrow, t, T, b, h);
        const float* vb = tok_base(vc, vcur, btrow, t, T, b, h);
        klo = *(const f2*)(kb + dk);
        khi = *(const f2*)(kb + 64 + dk);
        vv  = *(const f4*)(vb + d0v);
    }
    for (; t < hi; t += 8) {
        // prefetch next token
        const int tn = t + 8;
        f2 klon = {}, khin = {};
        f4 vn = {};
        if (tn < hi) {
            const float* kb = tok_base(kc, kcur, btrow, tn, T, b, h);
            const float* vb = tok_base(vc, vcur, btrow, tn, T, b, h);
            klon = *(const f2*)(kb + dk);
            khin = *(const f2*)(kb + 64 + dk);
            vn   = *(const f4*)(vb + d0v);
        }

        f4 cs;
        if (useTable) {
            cs = *(const f4*)(tab + (size_t)t * 128 + 4 * il);
        } else {
            float ss, cc;
            sincosf((float)t * invf0, &ss, &cc); cs.x = cc; cs.y = ss;
            sincosf((float)t * invf1, &ss, &cc); cs.z = cc; cs.w = ss;
        }
        f4 kr;
        kr.x = klo.x * cs.x - khi.x * cs.y;
        kr.y = klo.y * cs.z - khi.y * cs.w;
        kr.z = khi.x * cs.x + klo.x * cs.y;
        kr.w = khi.y * cs.z + klo.y * cs.w;

        float s0 = qr[0].x * kr.x + qr[0].y * kr.y + qr[0].z * kr.z + qr[0].w * kr.w;
        float s1 = qr[1].x * kr.x + qr[1].y * kr.y + qr[1].z * kr.z + qr[1].w * kr.w;
        float s2 = qr[2].x * kr.x + qr[2].y * kr.y + qr[2].z * kr.z + qr[2].w * kr.w;
        float s3 = qr[3].x * kr.x + qr[3].y * kr.y + qr[3].z * kr.z + qr[3].w * kr.w;
#pragma unroll
        for (int msk = 16; msk >= 1; msk >>= 1) {
            s0 += __shfl_xor(s0, msk);
            s1 += __shfl_xor(s1, msk);
            s2 += __shfl_xor(s2, msk);
            s3 += __shfl_xor(s3, msk);
        }
        float sarr[4] = {s0, s1, s2, s3};
#pragma unroll
        for (int g = 0; g < 4; ++g) {
            float sc = sarr[g];
            if (sc > m[g]) {                     // lazy rescale: rare (~log T times)
                float corr = __expf(m[g] - sc);
                l[g] *= corr;
                o[g] *= corr;
                m[g] = sc;
            }
            float p = __expf(sc - m[g]);
            l[g] += p;
            o[g] += p * vv;
        }
        klo = klon; khi = khin; vv = vn;
    }

    // --- combine the two half-waves of each wave ---
#pragma unroll
    for (int g = 0; g < 4; ++g) {
        float mo = __shfl_xor(m[g], 32);
        float M  = fmaxf(m[g], mo);
        float w  = (m[g] > -INFINITY) ? __expf(m[g] - M) : 0.f;
        float lw = l[g] * w;
        float Lc = lw + __shfl_xor(lw, 32);
        f4 ow = o[g] * w;
        f4 Oc;
        Oc.x = ow.x + __shfl_xor(ow.x, 32);
        Oc.y = ow.y + __shfl_xor(ow.y, 32);
        Oc.z = ow.z + __shfl_xor(ow.z, 32);
        Oc.w = ow.w + __shfl_xor(ow.w, 32);
        m[g] = M; l[g] = Lc; o[g] = Oc;
    }

    // --- cross-wave flash combine via LDS (4 waves) ---
    __shared__ float lm[4][4];
    __shared__ float ll[4][4];
    __shared__ float lodata[4][4][HD];
    const int w = tid >> 6;
    if ((tid & 32) == 0) {
        if (il == 0) {
#pragma unroll
            for (int g = 0; g < 4; ++g) { lm[w][g] = m[g]; ll[w][g] = l[g]; }
        }
#pragma unroll
        for (int g = 0; g < 4; ++g)
            *(f4*)(&lodata[w][g][d0v]) = o[g];
    }
    __syncthreads();

    // 256 threads cover 4 heads x 128 dims: each thread does g0 and g0+2
    {
        const int d  = tid & 127;
        const int g0 = tid >> 7;       // 0 or 1
#pragma unroll
        for (int gg = g0; gg < 4; gg += 2) {
            float M = -INFINITY;
#pragma unroll
            for (int i = 0; i < 4; ++i) M = fmaxf(M, lm[i][gg]);
            float L = 0.f, O = 0.f;
#pragma unroll
            for (int i = 0; i < 4; ++i) {
                float wgt = __expf(lm[i][gg] - M);
                L += wgt * ll[i][gg];
                O += wgt * lodata[i][gg][d];
            }
            if (S == 1) {
                out[(size_t)b * (NQH * HD) + (size_t)(h * GQA + gg) * HD + d] = O / L;
            } else {
                int pidx = blockIdx.x * 4 + gg;
                po[(size_t)pidx * HD + d] = O;
                if (d == 0) { pm[pidx] = M; pl[pidx] = L; }
            }
        }
    }
}

__global__ void combine_kernel(
    const float* __restrict__ pm,
    const float* __restrict__ pl,
    const float* __restrict__ po,
    float* __restrict__ out, int S)
{
    int i = blockIdx.x * blockDim.x + threadIdx.x;   // over B*NQH*HD
    int d  = i & 127;
    int qh = (i >> 7) & 31;
    int b  = i >> 12;
    int h  = qh >> 2;
    int g  = qh & 3;
    int base = ((b * NKVH + h) * S) * 4 + g;
    float M = -INFINITY;
    for (int s = 0; s < S; ++s) M = fmaxf(M, pm[base + s * 4]);
    float L = 0.f, O = 0.f;
    for (int s = 0; s < S; ++s) {
        float wgt = __expf(pm[base + s * 4] - M);
        L += wgt * pl[base + s * 4];
        O += wgt * po[(size_t)(base + s * 4) * HD + d];
    }
    out[i] = O / L;
}

extern "C" void kernel_launch(void* const* d_in, const int* in_sizes, int n_in,
                              void* d_out, int out_size, void* d_ws, size_t ws_size,
                              hipStream_t stream) {
    const float* q  = (const float*)d_in[0];
    const float* k  = (const float*)d_in[1];
    const float* v  = (const float*)d_in[2];
    const float* kc = (const float*)d_in[3];
    const float* vc = (const float*)d_in[4];
    const int*   bt = (const int*)d_in[5];
    int B  = in_sizes[0] / (NQH * HD);
    int nb = in_sizes[5] / B;
    int T  = nb * PBLK;

    float* out = (float*)d_out;
    char*  ws  = (char*)d_ws;

    size_t tabBytes = (size_t)(T + 1) * 128 * sizeof(float);
    size_t off = (tabBytes + 255) & ~(size_t)255;

    int S = 8;
    int nblk = B * NKVH * S;
    size_t pmB = (size_t)nblk * 4 * sizeof(float);
    size_t poB = (size_t)nblk * 4 * HD * sizeof(float);
    size_t need = off + 2 * pmB + poB;

    int useTable = (ws_size >= tabBytes) ? 1 : 0;
    if (ws_size < need) S = 1;   // fallback: single-pass direct write

    float* tab = (float*)ws;
    float* pm  = (float*)(ws + off);
    float* pl  = (float*)(ws + off + pmB);
    float* po  = (float*)(ws + off + 2 * pmB);

    if (useTable) {
        int total = (T + 1) * 64;
        rope_table_kernel<<<(total + 255) / 256, 256, 0, stream>>>(tab, T);
    }
    paged_attn_kernel<<<B * NKVH * S, 256, 0, stream>>>(
        q, k, v, kc, vc, bt, tab, out, pm, pl, po, T, nb, S, useTable);
    if (S > 1) {
        int totalOut = B * NQH * HD;
        combine_kernel<<<(totalOut + 255) / 256, 256, 0, stream>>>(pm, pl, po, out, S);
    }
}